// Round 11
// baseline (171.262 us; speedup 1.0000x reference)
//
#include <hip/hip_runtime.h>

// LocalWindowAttn: B=32, H=W=56, D=256, WS=7, NHEAD=8, hd=32
// tokens = 100352, windows = 2048
// Fused plan: convert (X,W->f16) -> qkv_attn (proj+attn fused, o in ws) -> out_gemm
// d_out scratch (dead before out_gemm writes): Xh fp16 + Wqh fp16
// ws: Oh f16 [NTOK,256] (51.4MB) + Woh f16 [256,256]

using f16   = _Float16;
using f16x4 = __attribute__((ext_vector_type(4))) _Float16;
using f16x8 = __attribute__((ext_vector_type(8))) _Float16;
using f32x4 = __attribute__((ext_vector_type(4))) float;

#define NTOK   100352
#define DMODEL 256
#define QKVN   768
#define OH_BYTES 51380224ull   // NTOK*256*2
#define WO_HALVES 65536        // 256*256

typedef const __attribute__((address_space(1))) unsigned int* as1_u32p;
typedef __attribute__((address_space(3))) unsigned int* as3_u32p;

__device__ __forceinline__ void gload16(const void* g, void* l) {
    __builtin_amdgcn_global_load_lds((as1_u32p)g, (as3_u32p)l, 16, 0, 0);
}

__device__ __forceinline__ f16x8 zero8() {
    f16x8 z;
#pragma unroll
    for (int i = 0; i < 8; ++i) z[i] = (f16)0;
    return z;
}

// ---------------- Kernel 0: fp32 -> fp16 convert (X, in_proj_w scaled, out_w) ----------------
#define XV4   6422528   // 100352*256/4
#define WQV4  49152     // 768*256/4
#define WOV4  16384     // 256*256/4
__global__ __launch_bounds__(256) void convert_all(
    const float* __restrict__ X, const float* __restrict__ Wq,
    const float* __restrict__ Wo,
    f16* __restrict__ Xh, f16* __restrict__ Wqh, f16* __restrict__ Woh)
{
    const float scale = 0.17677669529663687f;  // 1/sqrt(32)
    const int total = XV4 + WQV4 + WOV4;
    for (int i = blockIdx.x * blockDim.x + threadIdx.x; i < total;
         i += gridDim.x * blockDim.x) {
        float4 f;
        f16x4 h;
        if (i < XV4) {
            f = reinterpret_cast<const float4*>(X)[i];
            h[0]=(f16)f.x; h[1]=(f16)f.y; h[2]=(f16)f.z; h[3]=(f16)f.w;
            reinterpret_cast<f16x4*>(Xh)[i] = h;
        } else if (i < XV4 + WQV4) {
            int idx = i - XV4;
            int row = idx >> 6;          // 64 vec4 per 256-col row
            float sc = (row < 256) ? scale : 1.0f;
            f = reinterpret_cast<const float4*>(Wq)[idx];
            h[0]=(f16)(f.x*sc); h[1]=(f16)(f.y*sc); h[2]=(f16)(f.z*sc); h[3]=(f16)(f.w*sc);
            reinterpret_cast<f16x4*>(Wqh)[idx] = h;
        } else if (Woh) {
            int idx = i - XV4 - WQV4;
            f = reinterpret_cast<const float4*>(Wo)[idx];
            h[0]=(f16)f.x; h[1]=(f16)f.y; h[2]=(f16)f.z; h[3]=(f16)f.w;
            reinterpret_cast<f16x4*>(Woh)[idx] = h;
        }
    }
}

// ---------------- Kernel 1: fused QKV-projection + window attention ----------------
// Block = (window, 4 heads), 256 thr, wave = head. X window staged once in LDS
// (gload16, 32-slot XOR swizzle both-sides). Per wave: 3 GEMM chunks
// ([64,256]x[256,32], W b-frags from L2), D-layout -> fragment layout via
// per-wave LDS transpose (same-wave DS ops are in-order: no barriers), then
// the R4-verified swapped-QK^T attention. o -> compact [NTOK,256] f16.
__global__ __launch_bounds__(256) void qkv_attn(
    const f16* __restrict__ Xh,     // [NTOK,256]
    const f16* __restrict__ Wqh,    // [768,256] f16, q rows pre-scaled
    const float* __restrict__ bias, // [768]
    f16* __restrict__ Oh)           // [NTOK,256]
{
    __shared__ f16 Xw[49 * 256];    // 25,088 B
    __shared__ f16 P[4][64][68];    // 34,816 B (transpose buf, then softmax P)
    __shared__ f16 Vt[4][32][68];   // 17,408 B
    const int tid  = threadIdx.x;
    const int lane = tid & 63;
    const int w    = tid >> 6;
    const int bx   = blockIdx.x;
    const int win  = bx >> 1;
    const int h    = ((bx & 1) << 2) + w;
    const int b = win >> 6, wh = (win >> 3) & 7, ww = win & 7;
    const int base = (b * 56 + wh * 7) * 56 + ww * 7;
    const int g = lane >> 4, lr = lane & 15;
    const float scale = 0.17677669529663687f;

    auto tok = [&](int row) { int rr = row / 7; return base + rr * 56 + (row - rr * 7); };

    // stage X window: 1568 16B slots, linear dest, source-swizzled (rule 21)
#pragma unroll
    for (int i = 0; i < 7; ++i) {
        int s = tid + i * 256;
        if (s < 1568) {
            int row = s >> 5, sl = s & 31;
            int ss  = sl ^ (row & 31);
            gload16(Xh + (size_t)tok(row) * 256 + ss * 8, &Xw[s * 8]);
        }
    }
    __syncthreads();

    // GEMM chunk: acc[mi][nb] = D[tok][d] for this head's 32 dims of section sec
    auto chunk = [&](int sec, f32x4 (&acc)[4][2]) {
        const f16* Ws = Wqh + (size_t)((sec << 8) + (h << 5)) * 256;
#pragma unroll
        for (int kstep = 0; kstep < 8; ++kstep) {
            f16x8 a[4], bf[2];
#pragma unroll
            for (int mi = 0; mi < 4; ++mi) {
                int row = mi * 16 + lr;
                if (row < 49) {
                    int sl = ((kstep << 2) + g) ^ (row & 31);   // swizzled read
                    a[mi] = *reinterpret_cast<const f16x8*>(&Xw[row * 256 + sl * 8]);
                } else a[mi] = zero8();
            }
#pragma unroll
            for (int nb = 0; nb < 2; ++nb)
                bf[nb] = *reinterpret_cast<const f16x8*>(
                    Ws + (size_t)(nb * 16 + lr) * 256 + (kstep << 5) + g * 8);
#pragma unroll
            for (int mi = 0; mi < 4; ++mi)
#pragma unroll
                for (int nb = 0; nb < 2; ++nb)
                    acc[mi][nb] = __builtin_amdgcn_mfma_f32_16x16x32_f16(a[mi], bf[nb], acc[mi][nb], 0, 0, 0);
        }
    };

    f16x8 kf[4], qf[4];
    // ---- K chunk -> P-transpose ([tok][d]) -> kf frags ----
    {
        f32x4 acc[4][2] = {};
        chunk(1, acc);
        float bv[2] = { bias[256 + h * 32 + lr], bias[256 + h * 32 + 16 + lr] };
#pragma unroll
        for (int nb = 0; nb < 2; ++nb)
#pragma unroll
            for (int mi = 0; mi < 4; ++mi)
#pragma unroll
                for (int r = 0; r < 4; ++r) {
                    int row = mi * 16 + g * 4 + r;
                    P[w][row][nb * 16 + lr] =
                        (row < 49) ? (f16)(acc[mi][nb][r] + bv[nb]) : (f16)0;
                }
#pragma unroll
        for (int i = 0; i < 4; ++i)
            kf[i] = *reinterpret_cast<const f16x8*>(&P[w][i * 16 + lr][g * 8]);
    }
    // ---- Q chunk -> P-transpose (reuse; kf already in regs) -> qf frags ----
    {
        f32x4 acc[4][2] = {};
        chunk(0, acc);
        float bv[2] = { bias[h * 32 + lr] * scale, bias[h * 32 + 16 + lr] * scale };
#pragma unroll
        for (int nb = 0; nb < 2; ++nb)
#pragma unroll
            for (int mi = 0; mi < 4; ++mi)
#pragma unroll
                for (int r = 0; r < 4; ++r) {
                    int row = mi * 16 + g * 4 + r;
                    P[w][row][nb * 16 + lr] =
                        (row < 49) ? (f16)(acc[mi][nb][r] + bv[nb]) : (f16)0;
                }
#pragma unroll
        for (int i = 0; i < 4; ++i)
            qf[i] = *reinterpret_cast<const f16x8*>(&P[w][i * 16 + lr][g * 8]);
    }
    // ---- V chunk -> Vt[d][tok] (invalid tokens zeroed) ----
    {
        f32x4 acc[4][2] = {};
        chunk(2, acc);
        float bv[2] = { bias[512 + h * 32 + lr], bias[512 + h * 32 + 16 + lr] };
#pragma unroll
        for (int nb = 0; nb < 2; ++nb)
#pragma unroll
            for (int mi = 0; mi < 4; ++mi)
#pragma unroll
                for (int r = 0; r < 4; ++r) {
                    int row = mi * 16 + g * 4 + r;
                    Vt[w][nb * 16 + lr][row] =
                        (row < 49) ? (f16)(acc[mi][nb][r] + bv[nb]) : (f16)0;
                }
    }

    // ---- scores (swapped): s[ki][qi] -> lane holds S[q=16qi+lr][k=16ki+4g+r] ----
    f32x4 s[4][4] = {};
#pragma unroll
    for (int ki = 0; ki < 4; ++ki)
#pragma unroll
        for (int qi = 0; qi < 4; ++qi)
            s[ki][qi] = __builtin_amdgcn_mfma_f32_16x16x32_f16(kf[ki], qf[qi], s[ki][qi], 0, 0, 0);

    // ---- softmax (lane-local + 2 shfl; kf rows>=49 are zero -> exp(0)=1, excluded from sum) ----
#pragma unroll
    for (int qi = 0; qi < 4; ++qi) {
        float e[4][4];
        float sum = 0.f;
#pragma unroll
        for (int ki = 0; ki < 4; ++ki)
#pragma unroll
            for (int r = 0; r < 4; ++r)
                e[ki][r] = __expf(s[ki][qi][r]);
#pragma unroll
        for (int ki = 0; ki < 3; ++ki)
#pragma unroll
            for (int r = 0; r < 4; ++r)
                sum += e[ki][r];
        sum += (g == 0) ? e[3][0] : 0.f;   // k=48 is the only valid ki=3 slot
        sum += __shfl_xor(sum, 16, 64);
        sum += __shfl_xor(sum, 32, 64);
        float is = 1.f / sum;
#pragma unroll
        for (int ki = 0; ki < 4; ++ki) {
            f16x4 pw;
            pw[0] = (f16)(e[ki][0] * is);
            pw[1] = (f16)(e[ki][1] * is);
            pw[2] = (f16)(e[ki][2] * is);
            pw[3] = (f16)(e[ki][3] * is);
            *reinterpret_cast<f16x4*>(&P[w][qi * 16 + lr][ki * 16 + g * 4]) = pw;
        }
    }

    // ---- PV (invalid P cols * zeroed Vt rows = 0) ----
    f32x4 o[4][2] = {};
#pragma unroll
    for (int ks = 0; ks < 2; ++ks) {
        f16x8 pa[4], vb[2];
#pragma unroll
        for (int mi = 0; mi < 4; ++mi)
            pa[mi] = *reinterpret_cast<const f16x8*>(&P[w][mi * 16 + lr][ks * 32 + g * 8]);
#pragma unroll
        for (int ni = 0; ni < 2; ++ni)
            vb[ni] = *reinterpret_cast<const f16x8*>(&Vt[w][ni * 16 + lr][ks * 32 + g * 8]);
#pragma unroll
        for (int mi = 0; mi < 4; ++mi)
#pragma unroll
            for (int ni = 0; ni < 2; ++ni)
                o[mi][ni] = __builtin_amdgcn_mfma_f32_16x16x32_f16(pa[mi], vb[ni], o[mi][ni], 0, 0, 0);
    }
    // ---- store o to compact [NTOK,256] ----
#pragma unroll
    for (int mi = 0; mi < 4; ++mi)
#pragma unroll
        for (int r = 0; r < 4; ++r) {
            int row = mi * 16 + g * 4 + r;
            if (row < 49) {
                size_t off = (size_t)tok(row) * 256 + h * 32;
#pragma unroll
                for (int ni = 0; ni < 2; ++ni)
                    Oh[off + ni * 16 + lr] = (f16)o[mi][ni][r];
            }
        }
}

// ---------------- Kernel 2a: out = o @ Woh^T + b (all-gload16, A stride 256) ----------------
__global__ __launch_bounds__(256) void out_gemm_f16(
    const f16* __restrict__ O,      // [NTOK,256] f16
    const f16* __restrict__ Wh,     // [256,256] f16
    const float* __restrict__ bias,
    float* __restrict__ OUT)        // [100352,256]
{
    __shared__ f16 As[128 * 64];
    __shared__ f16 Bs[128 * 64];
    const int tid  = threadIdx.x;
    const int lane = tid & 63;
    const int wave = tid >> 6;
    int wg = blockIdx.x;
    const int cpx = (NTOK / 128) * (DMODEL / 128) / 8;   // 1568/8
    wg = (wg & 7) * cpx + (wg >> 3);
    const int m0 = (wg / (DMODEL / 128)) * 128;
    const int n0 = (wg % (DMODEL / 128)) * 128;
    const int wm = (wave >> 1) * 64;
    const int wn = (wave & 1) * 64;
    const int g  = lane >> 4;
    const int lr = lane & 15;

    f32x4 acc[4][4] = {};

    for (int k0 = 0; k0 < 256; k0 += 64) {
#pragma unroll
        for (int j = 0; j < 4; ++j) {
            int s   = tid + j * 256;
            int row = s >> 3, sl = s & 7;
            int ss  = sl ^ (row & 7);
            gload16(O + (size_t)(m0 + row) * 256 + k0 + ss * 8, &As[s * 8]);
            gload16(Wh + (size_t)(n0 + row) * 256 + k0 + ss * 8, &Bs[s * 8]);
        }
        __syncthreads();
#pragma unroll
        for (int ks = 0; ks < 2; ++ks) {
            f16x8 a[4], b[4];
#pragma unroll
            for (int i = 0; i < 4; ++i) {
                int row = wm + i * 16 + lr;
                int c   = ((ks << 2) + g) ^ (row & 7);
                a[i] = *reinterpret_cast<const f16x8*>(&As[row * 64 + c * 8]);
            }
#pragma unroll
            for (int i = 0; i < 4; ++i) {
                int row = wn + i * 16 + lr;
                int c   = ((ks << 2) + g) ^ (row & 7);
                b[i] = *reinterpret_cast<const f16x8*>(&Bs[row * 64 + c * 8]);
            }
#pragma unroll
            for (int mi = 0; mi < 4; ++mi)
#pragma unroll
                for (int ni = 0; ni < 4; ++ni)
                    acc[mi][ni] = __builtin_amdgcn_mfma_f32_16x16x32_f16(a[mi], b[ni], acc[mi][ni], 0, 0, 0);
        }
        __syncthreads();
    }
#pragma unroll
    for (int ni = 0; ni < 4; ++ni) {
        int n = n0 + wn + ni * 16 + lr;
        float bv = bias[n];
#pragma unroll
        for (int mi = 0; mi < 4; ++mi)
#pragma unroll
            for (int r = 0; r < 4; ++r) {
                int m = m0 + wm + mi * 16 + g * 4 + r;
                OUT[(size_t)m * 256 + n] = acc[mi][ni][r] + bv;
            }
    }
}

// ---------------- Kernel 2b: fallback (B cvt-staged, A stride 256) ----------------
__global__ __launch_bounds__(256) void out_gemm_cvt(
    const f16* __restrict__ O,
    const float* __restrict__ W,    // [256,256] fp32
    const float* __restrict__ bias,
    float* __restrict__ OUT)
{
    __shared__ f16 As[128 * 64];
    __shared__ f16 Bs[128][72];
    const int tid  = threadIdx.x;
    const int lane = tid & 63;
    const int wave = tid >> 6;
    int wg = blockIdx.x;
    const int cpx = (NTOK / 128) * (DMODEL / 128) / 8;
    wg = (wg & 7) * cpx + (wg >> 3);
    const int m0 = (wg / (DMODEL / 128)) * 128;
    const int n0 = (wg % (DMODEL / 128)) * 128;
    const int wm = (wave >> 1) * 64;
    const int wn = (wave & 1) * 64;
    const int g  = lane >> 4;
    const int lr = lane & 15;

    f32x4 acc[4][4] = {};

    for (int k0 = 0; k0 < 256; k0 += 64) {
#pragma unroll
        for (int j = 0; j < 4; ++j) {
            int s   = tid + j * 256;
            int row = s >> 3, sl = s & 7;
            int ss  = sl ^ (row & 7);
            gload16(O + (size_t)(m0 + row) * 256 + k0 + ss * 8, &As[s * 8]);
        }
#pragma unroll
        for (int j = 0; j < 8; ++j) {
            int v = tid + j * 256;
            int row = v >> 4, cv = v & 15;
            float4 f = *reinterpret_cast<const float4*>(W + (size_t)(n0 + row) * 256 + k0 + cv * 4);
            f16x4 h; h[0]=(f16)f.x; h[1]=(f16)f.y; h[2]=(f16)f.z; h[3]=(f16)f.w;
            *reinterpret_cast<f16x4*>(&Bs[row][cv * 4]) = h;
        }
        __syncthreads();
#pragma unroll
        for (int ks = 0; ks < 2; ++ks) {
            f16x8 a[4], b[4];
#pragma unroll
            for (int i = 0; i < 4; ++i) {
                int row = wm + i * 16 + lr;
                int c   = ((ks << 2) + g) ^ (row & 7);
                a[i] = *reinterpret_cast<const f16x8*>(&As[row * 64 + c * 8]);
            }
#pragma unroll
            for (int i = 0; i < 4; ++i)
                b[i] = *reinterpret_cast<const f16x8*>(&Bs[wn + i * 16 + lr][ks * 32 + g * 8]);
#pragma unroll
            for (int mi = 0; mi < 4; ++mi)
#pragma unroll
                for (int ni = 0; ni < 4; ++ni)
                    acc[mi][ni] = __builtin_amdgcn_mfma_f32_16x16x32_f16(a[mi], b[ni], acc[mi][ni], 0, 0, 0);
        }
        __syncthreads();
    }
#pragma unroll
    for (int ni = 0; ni < 4; ++ni) {
        int n = n0 + wn + ni * 16 + lr;
        float bv = bias[n];
#pragma unroll
        for (int mi = 0; mi < 4; ++mi)
#pragma unroll
            for (int r = 0; r < 4; ++r) {
                int m = m0 + wm + mi * 16 + g * 4 + r;
                OUT[(size_t)m * 256 + n] = acc[mi][ni][r] + bv;
            }
    }
}

extern "C" void kernel_launch(void* const* d_in, const int* in_sizes, int n_in,
                              void* d_out, int out_size, void* d_ws, size_t ws_size,
                              hipStream_t stream) {
    const float* x     = (const float*)d_in[0];
    const float* in_w  = (const float*)d_in[1];
    const float* in_b  = (const float*)d_in[2];
    const float* out_w = (const float*)d_in[3];
    const float* out_b = (const float*)d_in[4];
    float* out = (float*)d_out;

    // ws: Oh (attention output, f16 [NTOK,256]) + Woh (f16 out_w)
    f16* oh = (f16*)d_ws;
    const bool tailok = ws_size >= OH_BYTES + (size_t)WO_HALVES * 2;
    f16* woh = tailok ? (f16*)((char*)d_ws + OH_BYTES) : nullptr;

    // d_out front as pre-GEMM scratch (dead by the time out_gemm writes)
    f16* xh  = (f16*)d_out;              // 25,690,112 halves
    f16* wqh = xh + (size_t)NTOK * 256;  // 196,608 halves (q rows pre-scaled)

    convert_all<<<2048, 256, 0, stream>>>(x, in_w, out_w, xh, wqh, woh);

    qkv_attn<<<4096, 256, 0, stream>>>(xh, wqh, in_b, oh);

    if (tailok)
        out_gemm_f16<<<(NTOK / 128) * (DMODEL / 128), 256, 0, stream>>>(oh, woh, out_b, out);
    else
        out_gemm_cvt<<<(NTOK / 128) * (DMODEL / 128), 256, 0, stream>>>(oh, out_w, out_b, out);
}

// Round 12
// 147.695 us; speedup vs baseline: 1.1596x; 1.1596x over previous
//
#include <hip/hip_runtime.h>

// LocalWindowAttn: B=32, H=W=56, D=256, WS=7, NHEAD=8, hd=32
// tokens = 100352, windows = 2048
// ws: qkv fp16 [100352,768] = 154,140,672 B (+ f16 out_w in tail if room)
// d_out scratch (dead before out_gemm writes): Xh fp16 + Wqh fp16

using f16   = _Float16;
using f16x4 = __attribute__((ext_vector_type(4))) _Float16;
using f16x8 = __attribute__((ext_vector_type(8))) _Float16;
using f32x4 = __attribute__((ext_vector_type(4))) float;

#define NTOK   100352
#define DMODEL 256
#define QKVN   768
#define QKV_BYTES 154140672ull
#define WO_HALVES 65536    // 256*256

typedef const __attribute__((address_space(1))) unsigned int* as1_u32p;
typedef __attribute__((address_space(3))) unsigned int* as3_u32p;

__device__ __forceinline__ void gload16(const void* g, void* l) {
    __builtin_amdgcn_global_load_lds((as1_u32p)g, (as3_u32p)l, 16, 0, 0);
}

__device__ __forceinline__ f16x8 zero8() {
    f16x8 z;
#pragma unroll
    for (int i = 0; i < 8; ++i) z[i] = (f16)0;
    return z;
}

// ---------------- Kernel 0: fp32 -> fp16 convert (X, in_proj_w scaled, out_w) ----------------
#define XV4   6422528   // 100352*256/4
#define WQV4  49152     // 768*256/4
#define WOV4  16384     // 256*256/4
__global__ __launch_bounds__(256) void convert_all(
    const float* __restrict__ X, const float* __restrict__ Wq,
    const float* __restrict__ Wo,
    f16* __restrict__ Xh, f16* __restrict__ Wqh, f16* __restrict__ Woh)
{
    const float scale = 0.17677669529663687f;  // 1/sqrt(32)
    const int total = XV4 + WQV4 + WOV4;
    for (int i = blockIdx.x * blockDim.x + threadIdx.x; i < total;
         i += gridDim.x * blockDim.x) {
        float4 f;
        f16x4 h;
        if (i < XV4) {
            f = reinterpret_cast<const float4*>(X)[i];
            h[0]=(f16)f.x; h[1]=(f16)f.y; h[2]=(f16)f.z; h[3]=(f16)f.w;
            reinterpret_cast<f16x4*>(Xh)[i] = h;
        } else if (i < XV4 + WQV4) {
            int idx = i - XV4;
            int row = idx >> 6;          // 64 vec4 per 256-col row
            float sc = (row < 256) ? scale : 1.0f;
            f = reinterpret_cast<const float4*>(Wq)[idx];
            h[0]=(f16)(f.x*sc); h[1]=(f16)(f.y*sc); h[2]=(f16)(f.z*sc); h[3]=(f16)(f.w*sc);
            reinterpret_cast<f16x4*>(Wqh)[idx] = h;
        } else if (Woh) {
            int idx = i - XV4 - WQV4;
            f = reinterpret_cast<const float4*>(Wo)[idx];
            h[0]=(f16)f.x; h[1]=(f16)f.y; h[2]=(f16)f.z; h[3]=(f16)f.w;
            reinterpret_cast<f16x4*>(Woh)[idx] = h;
        }
    }
}

// ---------------- Kernel 1: qkv = Xh @ Wqh^T + b ----------------
// R4-verified main loop; MFMA operands swapped (R9-verified numerics:
// lane = 4 consecutive n at fixed m). Epilogue: stage C tile in LDS
// (aliased over As/Bs, row stride 136 -> 2-way-free b64 writes), then
// 8 x 16B coalesced global stores per thread (vs 64 x 2B scalar).
__global__ __launch_bounds__(256) void qkv_gemm(
    const f16* __restrict__ Xh,   // [100352,256]
    const f16* __restrict__ Wh,   // [768,256] f16, q rows pre-scaled
    const float* __restrict__ bias,
    f16* __restrict__ QKV)        // [100352,768]
{
    __shared__ __align__(16) f16 smem[17408];   // max(2*8192, 128*136) = 34816 B
    f16* As = smem;           // [128][64]
    f16* Bs = smem + 8192;    // [128][64]
    f16* Cs = smem;           // [128][136], reused after final barrier

    const int tid  = threadIdx.x;
    const int lane = tid & 63;
    const int wave = tid >> 6;
    int wg = blockIdx.x;
    const int cpx = (NTOK / 128) * (QKVN / 128) / 8;   // 4704/8
    wg = (wg & 7) * cpx + (wg >> 3);
    const int m0 = (wg / (QKVN / 128)) * 128;
    const int n0 = (wg % (QKVN / 128)) * 128;
    const int wm = (wave >> 1) * 64;
    const int wn = (wave & 1) * 64;
    const int g  = lane >> 4;
    const int lr = lane & 15;

    f32x4 acc[4][4] = {};   // acc[ni][mi]: D[n][m] (swapped operands)

    for (int k0 = 0; k0 < 256; k0 += 64) {
#pragma unroll
        for (int j = 0; j < 4; ++j) {
            int s   = tid + j * 256;          // 16B slot 0..1023
            int row = s >> 3, sl = s & 7;
            int ss  = sl ^ (row & 7);         // pre-swizzled source
            gload16(Xh + (size_t)(m0 + row) * 256 + k0 + ss * 8, &As[s * 8]);
            gload16(Wh + (size_t)(n0 + row) * 256 + k0 + ss * 8, &Bs[s * 8]);
        }
        __syncthreads();
#pragma unroll
        for (int ks = 0; ks < 2; ++ks) {
            f16x8 a[4], b[4];
#pragma unroll
            for (int i = 0; i < 4; ++i) {
                int row = wm + i * 16 + lr;
                int c   = ((ks << 2) + g) ^ (row & 7);  // swizzled read
                a[i] = *reinterpret_cast<const f16x8*>(&As[row * 64 + c * 8]);
            }
#pragma unroll
            for (int i = 0; i < 4; ++i) {
                int row = wn + i * 16 + lr;
                int c   = ((ks << 2) + g) ^ (row & 7);
                b[i] = *reinterpret_cast<const f16x8*>(&Bs[row * 64 + c * 8]);
            }
#pragma unroll
            for (int ni = 0; ni < 4; ++ni)
#pragma unroll
                for (int mi = 0; mi < 4; ++mi)
                    acc[ni][mi] = __builtin_amdgcn_mfma_f32_16x16x32_f16(b[ni], a[mi], acc[ni][mi], 0, 0, 0);
        }
        __syncthreads();   // last iteration: all As/Bs reads complete -> Cs reuse safe
    }

    // ---- epilogue: bias + stage to LDS [128][136] ----
    const float scale = 0.17677669529663687f;
#pragma unroll
    for (int ni = 0; ni < 4; ++ni) {
        int nloc = wn + ni * 16 + g * 4;              // local col, 4-aligned
        int ng   = n0 + nloc;
        float4 b4 = *reinterpret_cast<const float4*>(bias + ng);
        float sc = (ng < 256) ? scale : 1.0f;         // 256 boundary is 4-aligned
#pragma unroll
        for (int mi = 0; mi < 4; ++mi) {
            int mloc = wm + mi * 16 + lr;             // local row
            f16x4 pw;
            pw[0] = (f16)(acc[ni][mi][0] + b4.x * sc);
            pw[1] = (f16)(acc[ni][mi][1] + b4.y * sc);
            pw[2] = (f16)(acc[ni][mi][2] + b4.z * sc);
            pw[3] = (f16)(acc[ni][mi][3] + b4.w * sc);
            *reinterpret_cast<f16x4*>(&Cs[mloc * 136 + nloc]) = pw;
        }
    }
    __syncthreads();
    // ---- coalesced C-write: 8 x f16x8 per thread, 256B contiguous per 16 lanes ----
#pragma unroll
    for (int j = 0; j < 8; ++j) {
        int s    = tid + j * 256;         // 0..2047
        int row  = s >> 4, slot = s & 15;
        f16x8 v = *reinterpret_cast<const f16x8*>(&Cs[row * 136 + slot * 8]);
        *reinterpret_cast<f16x8*>(&QKV[(size_t)(m0 + row) * QKVN + n0 + slot * 8]) = v;
    }
}

// ---------------- Kernel 2: per-(window, head) attention (R4-verified) ----------------
__global__ __launch_bounds__(256) void win_attn(f16* __restrict__ QKV)
{
    __shared__ f16 Vt[4][32][68];   // per-wave [d][k]
    __shared__ f16 P[4][64][68];    // per-wave [q][k]
    const int tid  = threadIdx.x;
    const int lane = tid & 63;
    const int w    = tid >> 6;
    const int u    = blockIdx.x * 4 + w;   // unit = (window, head)
    const int win = u >> 3, h = u & 7;
    const int b = win >> 6, wh = (win >> 3) & 7, ww = win & 7;
    const int base = (b * 56 + wh * 7) * 56 + ww * 7;
    const int g = lane >> 4, lr = lane & 15;

    auto tok = [&](int row) { int rr = row / 7; return base + rr * 56 + (row - rr * 7); };

    f16x8 qf[4], kf[4];
#pragma unroll
    for (int i = 0; i < 4; ++i) {
        int row = i * 16 + lr;
        if (row < 49) {
            size_t off = (size_t)tok(row) * QKVN + h * 32 + g * 8;
            qf[i] = *reinterpret_cast<const f16x8*>(QKV + off);
            kf[i] = *reinterpret_cast<const f16x8*>(QKV + off + 256);
        } else { qf[i] = zero8(); kf[i] = zero8(); }
    }
    {
        int kk = lane;
        if (kk < 49) {
            size_t off = (size_t)tok(kk) * QKVN + 512 + h * 32;
            f16x8 vv[4];
#pragma unroll
            for (int j = 0; j < 4; ++j)
                vv[j] = *reinterpret_cast<const f16x8*>(QKV + off + j * 8);
#pragma unroll
            for (int j = 0; j < 4; ++j)
#pragma unroll
                for (int d = 0; d < 8; ++d) Vt[w][j * 8 + d][kk] = vv[j][d];
        } else {
#pragma unroll
            for (int d = 0; d < 32; ++d) Vt[w][d][kk] = (f16)0;
        }
    }
    f32x4 s[4][4] = {};
#pragma unroll
    for (int ki = 0; ki < 4; ++ki)
#pragma unroll
        for (int qi = 0; qi < 4; ++qi)
            s[ki][qi] = __builtin_amdgcn_mfma_f32_16x16x32_f16(kf[ki], qf[qi], s[ki][qi], 0, 0, 0);

#pragma unroll
    for (int qi = 0; qi < 4; ++qi) {
        float e[4][4];
        float sum = 0.f;
#pragma unroll
        for (int ki = 0; ki < 4; ++ki)
#pragma unroll
            for (int r = 0; r < 4; ++r)
                e[ki][r] = __expf(s[ki][qi][r]);
#pragma unroll
        for (int ki = 0; ki < 3; ++ki)
#pragma unroll
            for (int r = 0; r < 4; ++r)
                sum += e[ki][r];
        sum += (g == 0) ? e[3][0] : 0.f;   // k=48 is the only valid ki=3 slot
        sum += __shfl_xor(sum, 16, 64);
        sum += __shfl_xor(sum, 32, 64);
        float is = 1.f / sum;
#pragma unroll
        for (int ki = 0; ki < 4; ++ki) {
            f16x4 pw;
            pw[0] = (f16)(e[ki][0] * is);
            pw[1] = (f16)(e[ki][1] * is);
            pw[2] = (f16)(e[ki][2] * is);
            pw[3] = (f16)(e[ki][3] * is);
            *reinterpret_cast<f16x4*>(&P[w][qi * 16 + lr][ki * 16 + g * 4]) = pw;
        }
    }
    __syncthreads();

    f32x4 o[4][2] = {};
#pragma unroll
    for (int ks = 0; ks < 2; ++ks) {
        f16x8 pa[4], vb[2];
#pragma unroll
        for (int mi = 0; mi < 4; ++mi)
            pa[mi] = *reinterpret_cast<const f16x8*>(&P[w][mi * 16 + lr][ks * 32 + g * 8]);
#pragma unroll
        for (int ni = 0; ni < 2; ++ni)
            vb[ni] = *reinterpret_cast<const f16x8*>(&Vt[w][ni * 16 + lr][ks * 32 + g * 8]);
#pragma unroll
        for (int mi = 0; mi < 4; ++mi)
#pragma unroll
            for (int ni = 0; ni < 2; ++ni)
                o[mi][ni] = __builtin_amdgcn_mfma_f32_16x16x32_f16(pa[mi], vb[ni], o[mi][ni], 0, 0, 0);
    }
#pragma unroll
    for (int mi = 0; mi < 4; ++mi)
#pragma unroll
        for (int r = 0; r < 4; ++r) {
            int row = mi * 16 + g * 4 + r;
            if (row < 49) {
                size_t off = (size_t)tok(row) * QKVN + h * 32;
#pragma unroll
                for (int ni = 0; ni < 2; ++ni)
                    QKV[off + ni * 16 + lr] = (f16)o[mi][ni][r];
            }
        }
}

// ---------------- Kernel 3a: out = o @ Woh^T + b (R8/R10-verified, all-gload16) ----------------
__global__ __launch_bounds__(256) void out_gemm_f16(
    const f16* __restrict__ O,      // rows stride 768, first 256 halves = o
    const f16* __restrict__ Wh,     // [256,256] f16
    const float* __restrict__ bias,
    float* __restrict__ OUT)        // [100352,256]
{
    __shared__ f16 As[128 * 64];
    __shared__ f16 Bs[128 * 64];
    const int tid  = threadIdx.x;
    const int lane = tid & 63;
    const int wave = tid >> 6;
    int wg = blockIdx.x;
    const int cpx = (NTOK / 128) * (DMODEL / 128) / 8;   // 1568/8
    wg = (wg & 7) * cpx + (wg >> 3);
    const int m0 = (wg / (DMODEL / 128)) * 128;
    const int n0 = (wg % (DMODEL / 128)) * 128;
    const int wm = (wave >> 1) * 64;
    const int wn = (wave & 1) * 64;
    const int g  = lane >> 4;
    const int lr = lane & 15;

    f32x4 acc[4][4] = {};

    for (int k0 = 0; k0 < 256; k0 += 64) {
#pragma unroll
        for (int j = 0; j < 4; ++j) {
            int s   = tid + j * 256;
            int row = s >> 3, sl = s & 7;
            int ss  = sl ^ (row & 7);
            gload16(O + (size_t)(m0 + row) * QKVN + k0 + ss * 8, &As[s * 8]);
            gload16(Wh + (size_t)(n0 + row) * 256 + k0 + ss * 8, &Bs[s * 8]);
        }
        __syncthreads();
#pragma unroll
        for (int ks = 0; ks < 2; ++ks) {
            f16x8 a[4], b[4];
#pragma unroll
            for (int i = 0; i < 4; ++i) {
                int row = wm + i * 16 + lr;
                int c   = ((ks << 2) + g) ^ (row & 7);
                a[i] = *reinterpret_cast<const f16x8*>(&As[row * 64 + c * 8]);
            }
#pragma unroll
            for (int i = 0; i < 4; ++i) {
                int row = wn + i * 16 + lr;
                int c   = ((ks << 2) + g) ^ (row & 7);
                b[i] = *reinterpret_cast<const f16x8*>(&Bs[row * 64 + c * 8]);
            }
#pragma unroll
            for (int mi = 0; mi < 4; ++mi)
#pragma unroll
                for (int ni = 0; ni < 4; ++ni)
                    acc[mi][ni] = __builtin_amdgcn_mfma_f32_16x16x32_f16(a[mi], b[ni], acc[mi][ni], 0, 0, 0);
        }
        __syncthreads();
    }
#pragma unroll
    for (int ni = 0; ni < 4; ++ni) {
        int n = n0 + wn + ni * 16 + lr;
        float bv = bias[n];
#pragma unroll
        for (int mi = 0; mi < 4; ++mi)
#pragma unroll
            for (int r = 0; r < 4; ++r) {
                int m = m0 + wm + mi * 16 + g * 4 + r;
                OUT[(size_t)m * 256 + n] = acc[mi][ni][r] + bv;
            }
    }
}

// ---------------- Kernel 3b: fallback (B cvt-staged, R4-verified) ----------------
__global__ __launch_bounds__(256) void out_gemm_cvt(
    const f16* __restrict__ O,
    const float* __restrict__ W,    // [256,256] fp32
    const float* __restrict__ bias,
    float* __restrict__ OUT)
{
    __shared__ f16 As[128 * 64];
    __shared__ f16 Bs[128][72];
    const int tid  = threadIdx.x;
    const int lane = tid & 63;
    const int wave = tid >> 6;
    int wg = blockIdx.x;
    const int cpx = (NTOK / 128) * (DMODEL / 128) / 8;
    wg = (wg & 7) * cpx + (wg >> 3);
    const int m0 = (wg / (DMODEL / 128)) * 128;
    const int n0 = (wg % (DMODEL / 128)) * 128;
    const int wm = (wave >> 1) * 64;
    const int wn = (wave & 1) * 64;
    const int g  = lane >> 4;
    const int lr = lane & 15;

    f32x4 acc[4][4] = {};

    for (int k0 = 0; k0 < 256; k0 += 64) {
#pragma unroll
        for (int j = 0; j < 4; ++j) {
            int s   = tid + j * 256;
            int row = s >> 3, sl = s & 7;
            int ss  = sl ^ (row & 7);
            gload16(O + (size_t)(m0 + row) * QKVN + k0 + ss * 8, &As[s * 8]);
        }
#pragma unroll
        for (int j = 0; j < 8; ++j) {
            int v = tid + j * 256;
            int row = v >> 4, cv = v & 15;
            float4 f = *reinterpret_cast<const float4*>(W + (size_t)(n0 + row) * 256 + k0 + cv * 4);
            f16x4 h; h[0]=(f16)f.x; h[1]=(f16)f.y; h[2]=(f16)f.z; h[3]=(f16)f.w;
            *reinterpret_cast<f16x4*>(&Bs[row][cv * 4]) = h;
        }
        __syncthreads();
#pragma unroll
        for (int ks = 0; ks < 2; ++ks) {
            f16x8 a[4], b[4];
#pragma unroll
            for (int i = 0; i < 4; ++i) {
                int row = wm + i * 16 + lr;
                int c   = ((ks << 2) + g) ^ (row & 7);
                a[i] = *reinterpret_cast<const f16x8*>(&As[row * 64 + c * 8]);
            }
#pragma unroll
            for (int i = 0; i < 4; ++i)
                b[i] = *reinterpret_cast<const f16x8*>(&Bs[wn + i * 16 + lr][ks * 32 + g * 8]);
#pragma unroll
            for (int mi = 0; mi < 4; ++mi)
#pragma unroll
                for (int ni = 0; ni < 4; ++ni)
                    acc[mi][ni] = __builtin_amdgcn_mfma_f32_16x16x32_f16(a[mi], b[ni], acc[mi][ni], 0, 0, 0);
        }
        __syncthreads();
    }
#pragma unroll
    for (int ni = 0; ni < 4; ++ni) {
        int n = n0 + wn + ni * 16 + lr;
        float bv = bias[n];
#pragma unroll
        for (int mi = 0; mi < 4; ++mi)
#pragma unroll
            for (int r = 0; r < 4; ++r) {
                int m = m0 + wm + mi * 16 + g * 4 + r;
                OUT[(size_t)m * 256 + n] = acc[mi][ni][r] + bv;
            }
    }
}

extern "C" void kernel_launch(void* const* d_in, const int* in_sizes, int n_in,
                              void* d_out, int out_size, void* d_ws, size_t ws_size,
                              hipStream_t stream) {
    const float* x     = (const float*)d_in[0];
    const float* in_w  = (const float*)d_in[1];
    const float* in_b  = (const float*)d_in[2];
    const float* out_w = (const float*)d_in[3];
    const float* out_b = (const float*)d_in[4];
    float* out = (float*)d_out;
    f16* qkv = (f16*)d_ws;               // QKV_BYTES

    // d_out front as pre-GEMM scratch (dead by the time out_gemm writes)
    f16* xh  = (f16*)d_out;              // 25,690,112 halves
    f16* wqh = xh + (size_t)NTOK * 256;  // 196,608 halves (q rows pre-scaled)
    // Woh must NOT live in d_out (out_gemm writes race its own B reads) -> ws tail
    const bool tailok = ws_size >= QKV_BYTES + (size_t)WO_HALVES * 2;
    f16* woh = tailok ? (f16*)((char*)d_ws + QKV_BYTES) : nullptr;

    convert_all<<<2048, 256, 0, stream>>>(x, in_w, out_w, xh, wqh, woh);

    qkv_gemm<<<(NTOK / 128) * (QKVN / 128), 256, 0, stream>>>(xh, wqh, in_b, qkv);

    win_attn<<<4096, 256, 0, stream>>>(qkv);

    if (tailok)
        out_gemm_f16<<<(NTOK / 128) * (DMODEL / 128), 256, 0, stream>>>(qkv, woh, out_b, out);
    else
        out_gemm_cvt<<<(NTOK / 128) * (DMODEL / 128), 256, 0, stream>>>(qkv, out_w, out_b, out);
}